// Round 1
// baseline (80.489 us; speedup 1.0000x reference)
//
#include <hip/hip_runtime.h>

// Forward of symmetry-aware quaternion loss.
// out layout (float32, concatenated): loss[B] | x_near[B*4] | label_near[B*4]
//
// Per sample b:
//   u = x/||x||;  w = L(y)^T u  (so dot(u, qua_mul(y,q)) == dot(w, q))
//   over s < count[n[b]]: d_s = clip(dot(w, q_s), -1+eps, 1-eps)
//   branch1 min-angle = acos(max d), branch2 = acos(-min d); ties -> branch1,
//   within branch -> smallest s (matches jnp.argmin over [acos(d),acos(-d)]).
// 8 lanes per sample: class-4 (count=360) takes 45 loop iters; butterfly
// reduce (value,index) pairs over lanes with exact tie-break semantics.

__global__ __launch_bounds__(256) void quer_loss_fwd(
    const float* __restrict__ x,
    const float* __restrict__ y,
    const int*   __restrict__ n,
    const float* __restrict__ sym,   // [5,360,4]
    float* __restrict__ out,
    int B)
{
    const int tid   = blockIdx.x * blockDim.x + threadIdx.x;
    const int b     = tid >> 3;
    const int lane8 = tid & 7;
    if (b >= B) return;

    const int c = n[b];
    // counts = {1,2,4,12,360}; avoid runtime-indexed local array (goes to scratch)
    const int count = (c < 3) ? (1 << c) : ((c == 3) ? 12 : 360);

    const float4 xv = *(const float4*)(x + 4 * (long)b);
    const float4 yv = *(const float4*)(y + 4 * (long)b);

    const float inv = 1.0f / sqrtf(xv.x*xv.x + xv.y*xv.y + xv.z*xv.z + xv.w*xv.w);
    const float ux = xv.x*inv, uy = xv.y*inv, uz = xv.z*inv, uw = xv.w*inv;

    // w such that dot(u, qua_mul(y, q)) = q.x*wx + q.y*wy + q.z*wz + q.w*ww
    const float wx =  ux*yv.w - uy*yv.z + uz*yv.y - uw*yv.x;
    const float wy =  ux*yv.z + uy*yv.w - uz*yv.x - uw*yv.y;
    const float wz = -ux*yv.y + uy*yv.x + uz*yv.w - uw*yv.z;
    const float ww =  ux*yv.x + uy*yv.y + uz*yv.z + uw*yv.w;

    const float HI = 1.0f - 1e-6f;
    const float LO = -HI;

    float maxd = -2.0f; int smax = 0x7fffffff;
    float mind =  2.0f; int smin = 0x7fffffff;

    const float4* __restrict__ sq = (const float4*)sym + (long)c * 360;

    for (int s = lane8; s < count; s += 8) {
        const float4 q = sq[s];
        float d = q.x*wx + q.y*wy + q.z*wz + q.w*ww;
        d = fminf(fmaxf(d, LO), HI);
        if (d > maxd) { maxd = d; smax = s; }   // strict: keeps smallest s per lane
        if (d < mind) { mind = d; smin = s; }
    }

    // 8-lane butterfly reduce; tie -> smaller index (reference argmin order)
    #pragma unroll
    for (int m = 1; m <= 4; m <<= 1) {
        const float od = __shfl_xor(maxd, m);
        const int   os = __shfl_xor(smax, m);
        if (od > maxd || (od == maxd && os < smax)) { maxd = od; smax = os; }
        const float pd = __shfl_xor(mind, m);
        const int   ps = __shfl_xor(smin, m);
        if (pd < mind || (pd == mind && ps < smin)) { mind = pd; smin = ps; }
    }

    if (lane8 == 0) {
        // branch2 wins only strictly (flat-index order: branch1 block first)
        const bool b2   = (-mind) > maxd;
        const float dbest = b2 ? -mind : maxd;
        const float loss  = acosf(dbest);
        const int sbest   = b2 ? smin : smax;

        const float4 q = sq[sbest];
        // pos = qua_mul(p=y, q)  (reference formula)
        const float rx = q.w*yv.x + q.x*yv.w + q.y*yv.z - q.z*yv.y;
        const float ry = q.w*yv.y - q.x*yv.z + q.y*yv.w + q.z*yv.x;
        const float rz = q.w*yv.z + q.x*yv.y - q.y*yv.x + q.z*yv.w;
        const float rw = q.w*yv.w - q.x*yv.x - q.y*yv.y - q.z*yv.z;

        out[b] = loss;
        const float sgn = b2 ? -1.0f : 1.0f;
        *(float4*)(out + (long)B     + 4 * (long)b) =
            make_float4(sgn*xv.x, sgn*xv.y, sgn*xv.z, sgn*xv.w);
        *(float4*)(out + 5l * B + 4 * (long)b) =
            make_float4(rx, ry, rz, rw);
    }
}

extern "C" void kernel_launch(void* const* d_in, const int* in_sizes, int n_in,
                              void* d_out, int out_size, void* d_ws, size_t ws_size,
                              hipStream_t stream) {
    const float* x   = (const float*)d_in[0];
    const float* y   = (const float*)d_in[1];
    const int*   n   = (const int*)d_in[3];
    const float* sym = (const float*)d_in[4];
    float* out = (float*)d_out;

    const int B = in_sizes[3];            // element count of n
    const int threads = B * 8;            // 8 lanes per sample
    const int block = 256;
    const int grid = (threads + block - 1) / block;
    hipLaunchKernelGGL(quer_loss_fwd, dim3(grid), dim3(block), 0, stream,
                       x, y, n, sym, out, B);
}